// Round 7
// baseline (262.190 us; speedup 1.0000x reference)
//
#include <hip/hip_runtime.h>
#include <stdint.h>

#define SS 4096     // tokens per batch (H*W)
#define CC 64       // channels
#define BB 16       // batch

typedef unsigned short u16;
typedef __attribute__((ext_vector_type(8))) __bf16 bf16x8;
typedef __attribute__((ext_vector_type(8))) short short8;
typedef __attribute__((ext_vector_type(4))) float f32x4;

// pack two f32 -> two bf16 in one u32 (low = a, high = b), round-half-up
__device__ __forceinline__ uint32_t pkbf(float a, float b) {
    uint32_t ua = __float_as_uint(a) + 0x8000u;
    uint32_t ub = __float_as_uint(b) + 0x8000u;
    return __builtin_amdgcn_perm(ub, ua, 0x07060302u);
}

// ---------------------------------------------------------------------------
// Kernel W: weights fp32 -> bf16 scratch. wsb[mat][o*64+c], mat 0..3 =
// qw,kw,vw,ow.
// ---------------------------------------------------------------------------
__global__ void wpre_kernel(const float* __restrict__ qw, const float* __restrict__ kw,
                            const float* __restrict__ vw, const float* __restrict__ ow,
                            u16* __restrict__ wsb)
{
    int idx = blockIdx.x * 256 + threadIdx.x;               // pair 0..8191
    const float* src = (idx < 2048) ? qw : (idx < 4096) ? kw
                     : (idx < 6144) ? vw : ow;
    int pair = idx & 2047;
    ((uint32_t*)wsb)[idx] = pkbf(src[pair * 2], src[pair * 2 + 1]);
}

// ---------------------------------------------------------------------------
// Kernel A: QKV projection, barrier-free (unchanged from R6; left as the
// control while flash changes — if it's the mystery 80us it will surface
// in top-5 this round).
// ---------------------------------------------------------------------------
__global__ __launch_bounds__(256, 4) void qkv_kernel(
    const float* __restrict__ x, const u16* __restrict__ wsb,
    const float* __restrict__ qb, const float* __restrict__ kb,
    const float* __restrict__ vb,
    u16* __restrict__ Q, u16* __restrict__ K, u16* __restrict__ VT)
{
    const int b    = blockIdx.x & 15;
    const int s0   = (blockIdx.x >> 4) << 6;
    const int tid  = threadIdx.x;
    const int w    = tid >> 6;
    const int lane = tid & 63;
    const int lq   = lane & 15;
    const int quad = lane >> 4;

    __shared__ u16 bounce[4][16 * 72];

    const int sm = s0 + w * 16 + lq;
    const float* xp = x + (size_t)b * CC * SS + sm;
    float xf[16];
#pragma unroll
    for (int kc = 0; kc < 2; ++kc)
#pragma unroll
        for (int j = 0; j < 8; ++j)
            xf[kc * 8 + j] = xp[(size_t)(kc * 32 + quad * 8 + j) * SS];

    union { uint32_t u[4]; bf16x8 v; } A0, A1;
#pragma unroll
    for (int p = 0; p < 4; ++p) {
        A0.u[p] = pkbf(xf[2 * p],     xf[2 * p + 1]);
        A1.u[p] = pkbf(xf[8 + 2 * p], xf[8 + 2 * p + 1]);
    }

    const float QSCALE = 0.125f * 1.44269504088896340736f;

    for (int m = 0; m < 3; ++m) {
        const float* bsrc = (m == 0) ? qb : ((m == 1) ? kb : vb);
        const u16* wm = wsb + m * 4096;
        bf16x8 bfr[2][4];
#pragma unroll
        for (int kc = 0; kc < 2; ++kc)
#pragma unroll
            for (int nt = 0; nt < 4; ++nt)
                bfr[kc][nt] = *(const bf16x8*)&wm[(nt * 16 + lq) * 64 + kc * 32 + quad * 8];

        f32x4 acc[4];
#pragma unroll
        for (int nt = 0; nt < 4; ++nt) {
            float bv = bsrc[nt * 16 + lq];
            acc[nt] = (f32x4){bv, bv, bv, bv};
        }
#pragma unroll
        for (int nt = 0; nt < 4; ++nt) {
            acc[nt] = __builtin_amdgcn_mfma_f32_16x16x32_bf16(A0.v, bfr[0][nt], acc[nt], 0, 0, 0);
            acc[nt] = __builtin_amdgcn_mfma_f32_16x16x32_bf16(A1.v, bfr[1][nt], acc[nt], 0, 0, 0);
        }

        if (m == 2) {
#pragma unroll
            for (int nt = 0; nt < 4; ++nt) {
                int c = nt * 16 + lq;
                uint2 pv;
                pv.x = pkbf(acc[nt][0], acc[nt][1]);
                pv.y = pkbf(acc[nt][2], acc[nt][3]);
                *(uint2*)(VT + ((size_t)(b * CC + c)) * SS + s0 + w * 16 + quad * 4) = pv;
            }
        } else {
            const float scl = (m == 0) ? QSCALE : 1.0f;
            u16* bb = bounce[w];
#pragma unroll
            for (int nt = 0; nt < 4; ++nt)
#pragma unroll
                for (int r = 0; r < 4; ++r)
                    bb[(quad * 4 + r) * 72 + nt * 16 + lq] =
                        (u16)((__float_as_uint(acc[nt][r] * scl) + 0x8000u) >> 16);

            const int row = lane >> 2;
            const int ch  = (lane & 3) << 4;
            short8 v0 = *(const short8*)&bb[row * 72 + ch];
            short8 v1 = *(const short8*)&bb[row * 72 + ch + 8];
            u16* dst = ((m == 0) ? Q : K) + ((size_t)(b * SS + s0 + w * 16 + row)) * CC + ch;
            *(short8*)dst = v0;
            *(short8*)(dst + 8) = v1;
        }
    }
}

// ---------------------------------------------------------------------------
// Kernel B: flash attention + fused out-projection (R5 structure, V-DIRECT).
// 128 q/block, 2 q-groups/wave sharing K frags. K staged in LDS (double-
// buffered, one barrier/iter); V^T fragments loaded straight from global
// into registers (separate vmem pipe; kc-pair covers full 128B lines; all
// L2/L3-hot) -> LDS read traffic drops from 20 to 12 b128/wave-iter.
// Fixed-max softmax (|s| tiny), XOR-swizzled K tile, 144B-stride P rows.
// ---------------------------------------------------------------------------
__global__ __launch_bounds__(256, 2) void flash_kernel(
    const u16* __restrict__ Q, const u16* __restrict__ K,
    const u16* __restrict__ Vt, const u16* __restrict__ owb,
    const float* __restrict__ ob, float* __restrict__ out)
{
    const int b    = blockIdx.x & 15;          // batch-major: XCD gets 2 batches
    const int q0   = (blockIdx.x >> 4) << 7;   // 128 q per block
    const int tid  = threadIdx.x;
    const int w    = tid >> 6;
    const int lane = tid & 63;
    const int lq   = lane & 15;
    const int quad = lane >> 4;

    __shared__ u16 lds_k[2][64 * 64];      // K tile [key][c], swizzled
    __shared__ u16 lds_p[8][16 * 72];      // [wave][group] P / O bounce

    // Q B-frags for both groups
    bf16x8 qf[2][2];
#pragma unroll
    for (int g = 0; g < 2; ++g) {
        const u16* qp = Q + ((size_t)(b * SS + q0 + g * 64 + w * 16 + lq)) * CC + quad * 8;
        qf[g][0] = *(const bf16x8*)(qp);
        qf[g][1] = *(const bf16x8*)(qp + 32);
    }

    // V^T A-frag base pointers (per ct); advanced +64 elems (128B) per iter
    const u16* vp[4];
#pragma unroll
    for (int ct = 0; ct < 4; ++ct)
        vp[ct] = Vt + ((size_t)(b * CC + ct * 16 + lq)) * SS + quad * 8;

    f32x4 ot[2][4];
#pragma unroll
    for (int g = 0; g < 2; ++g)
#pragma unroll
        for (int ct = 0; ct < 4; ++ct) ot[g][ct] = (f32x4){0.f, 0.f, 0.f, 0.f};
    float lp[2][4] = {{0.f, 0.f, 0.f, 0.f}, {0.f, 0.f, 0.f, 0.f}};

    // K staging: thread covers row srow, 16B chunks 2a, 2a+1 (XOR-swizzled)
    const int srow = tid >> 2;
    const int a    = tid & 3;
    const u16* kg = K + ((size_t)(b * SS + srow)) * CC + a * 16;
    const int sw0 = srow * 64 + (((a << 1)    ) ^ (srow & 7)) * 8;
    const int sw1 = srow * 64 + (((a << 1) | 1) ^ (srow & 7)) * 8;

    {   // prologue: K tile 0 -> buf 0
        short8 k0 = *(const short8*)(kg);
        short8 k1 = *(const short8*)(kg + 8);
        *(short8*)&lds_k[0][sw0] = k0;
        *(short8*)&lds_k[0][sw1] = k1;
    }

    const int lsw = lq & 7;
    u16* pw0 = lds_p[(w << 1)];
    u16* pw1 = lds_p[(w << 1) | 1];

    for (int kt = 0; kt < 64; ++kt) {
        __syncthreads();
        const int buf = kt & 1;

        // V^T frags for THIS tile, straight from global (L2-hot; consumed
        // after S^T + softmax, ~500 cyc of slack covers the latency)
        bf16x8 vfr[2][4];
#pragma unroll
        for (int kc = 0; kc < 2; ++kc)
#pragma unroll
            for (int ct = 0; ct < 4; ++ct)
                vfr[kc][ct] = *(const bf16x8*)(vp[ct] + kc * 32);

        // prefetch next K tile (consumed at end of body)
        const int ktn = (kt + 1) & 63;
        const u16* kgn = kg + (size_t)ktn * (64 * CC);
        short8 nk0 = *(const short8*)(kgn);
        short8 nk1 = *(const short8*)(kgn + 8);

        // K frags loaded ONCE from LDS, feed both q-groups
        bf16x8 kf[2][4];
#pragma unroll
        for (int kc = 0; kc < 2; ++kc)
#pragma unroll
            for (int mt = 0; mt < 4; ++mt)
                kf[kc][mt] = *(const bf16x8*)
                    &lds_k[buf][(mt * 16 + lq) * 64 + (((kc << 2) + quad) ^ lsw) * 8];

        // S^T = K * Q^T for both groups
        f32x4 sa[2][4];
#pragma unroll
        for (int g = 0; g < 2; ++g)
#pragma unroll
            for (int mt = 0; mt < 4; ++mt) sa[g][mt] = (f32x4){0.f, 0.f, 0.f, 0.f};
#pragma unroll
        for (int g = 0; g < 2; ++g)
#pragma unroll
            for (int kc = 0; kc < 2; ++kc)
#pragma unroll
                for (int mt = 0; mt < 4; ++mt)
                    sa[g][mt] = __builtin_amdgcn_mfma_f32_16x16x32_bf16(
                        kf[kc][mt], qf[g][kc], sa[g][mt], 0, 0, 0);

        // softmax (fixed max): p = exp2(s), in-lane partial sums, P -> LDS
#pragma unroll
        for (int g = 0; g < 2; ++g) {
            u16* pw = g ? pw1 : pw0;
#pragma unroll
            for (int mt = 0; mt < 4; ++mt) {
                float p0 = __builtin_amdgcn_exp2f(sa[g][mt][0]);
                float p1 = __builtin_amdgcn_exp2f(sa[g][mt][1]);
                float p2 = __builtin_amdgcn_exp2f(sa[g][mt][2]);
                float p3 = __builtin_amdgcn_exp2f(sa[g][mt][3]);
                lp[g][0] += p0; lp[g][1] += p1; lp[g][2] += p2; lp[g][3] += p3;
                uint2 pv;
                pv.x = pkbf(p0, p1);
                pv.y = pkbf(p2, p3);
                *(uint2*)&pw[lq * 72 + mt * 16 + quad * 4] = pv;
            }
        }

        // O^T += V^T * P^T per group (V frags from registers)
#pragma unroll
        for (int g = 0; g < 2; ++g) {
            const u16* pw = g ? pw1 : pw0;
#pragma unroll
            for (int kc = 0; kc < 2; ++kc) {
                bf16x8 pf = *(const bf16x8*)&pw[lq * 72 + kc * 32 + quad * 8];
#pragma unroll
                for (int ct = 0; ct < 4; ++ct)
                    ot[g][ct] = __builtin_amdgcn_mfma_f32_16x16x32_bf16(
                        vfr[kc][ct], pf, ot[g][ct], 0, 0, 0);
            }
        }

        // advance V pointers, stage prefetched K tile into other buffer
#pragma unroll
        for (int ct = 0; ct < 4; ++ct) vp[ct] += 64;
        u16* lkd = lds_k[buf ^ 1];
        *(short8*)&lkd[sw0] = nk0;
        *(short8*)&lkd[sw1] = nk1;
    }

    // ---- fused out-projection epilogue ----
    bf16x8 wf[2][4];
#pragma unroll
    for (int kc = 0; kc < 2; ++kc)
#pragma unroll
        for (int nt = 0; nt < 4; ++nt)
            wf[kc][nt] = *(const bf16x8*)&owb[(nt * 16 + lq) * 64 + kc * 32 + quad * 8];
    float bias[4];
#pragma unroll
    for (int nt = 0; nt < 4; ++nt) bias[nt] = ob[nt * 16 + lq];

#pragma unroll
    for (int g = 0; g < 2; ++g) {
        float l = (lp[g][0] + lp[g][1]) + (lp[g][2] + lp[g][3]);
        l += __shfl_xor(l, 16);
        l += __shfl_xor(l, 32);
        const float inv = 1.0f / l;

        u16* po = g ? pw1 : pw0;
#pragma unroll
        for (int ct = 0; ct < 4; ++ct) {
            uint2 pv;
            pv.x = pkbf(ot[g][ct][0] * inv, ot[g][ct][1] * inv);
            pv.y = pkbf(ot[g][ct][2] * inv, ot[g][ct][3] * inv);
            *(uint2*)&po[lq * 72 + ct * 16 + quad * 4] = pv;
        }
        bf16x8 oa0 = *(const bf16x8*)&po[lq * 72 + quad * 8];
        bf16x8 oa1 = *(const bf16x8*)&po[lq * 72 + 32 + quad * 8];

        f32x4 acc[4];
#pragma unroll
        for (int nt = 0; nt < 4; ++nt)
            acc[nt] = (f32x4){bias[nt], bias[nt], bias[nt], bias[nt]};
#pragma unroll
        for (int nt = 0; nt < 4; ++nt) {
            acc[nt] = __builtin_amdgcn_mfma_f32_16x16x32_bf16(oa0, wf[0][nt], acc[nt], 0, 0, 0);
            acc[nt] = __builtin_amdgcn_mfma_f32_16x16x32_bf16(oa1, wf[1][nt], acc[nt], 0, 0, 0);
        }
#pragma unroll
        for (int nt = 0; nt < 4; ++nt) {
            float* dst = out + ((size_t)(b * CC + nt * 16 + lq)) * SS
                       + q0 + g * 64 + w * 16 + quad * 4;
            *(f32x4*)dst = acc[nt];
        }
    }
}

// ---------------------------------------------------------------------------
extern "C" void kernel_launch(void* const* d_in, const int* in_sizes, int n_in,
                              void* d_out, int out_size, void* d_ws, size_t ws_size,
                              hipStream_t stream)
{
    const float* x  = (const float*)d_in[0];
    const float* qw = (const float*)d_in[1];
    const float* qb = (const float*)d_in[2];
    const float* kw = (const float*)d_in[3];
    const float* kb = (const float*)d_in[4];
    const float* vw = (const float*)d_in[5];
    const float* vb = (const float*)d_in[6];
    const float* ow = (const float*)d_in[7];
    const float* ob = (const float*)d_in[8];
    float* out = (float*)d_out;

    const size_t T = (size_t)BB * SS * CC;
    u16* WSB = (u16*)d_ws;          // 4 mats x 4096 u16 = 32 KB
    u16* Q   = WSB + 4 * 4096;
    u16* K   = Q + T;
    u16* VT  = K + T;

    wpre_kernel<<<dim3(32), dim3(256), 0, stream>>>(qw, kw, vw, ow, WSB);
    qkv_kernel<<<dim3(BB * 64), dim3(256), 0, stream>>>(x, WSB, qb, kb, vb, Q, K, VT);
    flash_kernel<<<dim3(BB * 32), dim3(256), 0, stream>>>(Q, K, VT, WSB + 3 * 4096, ob, out);
}

// Round 8
// 224.434 us; speedup vs baseline: 1.1682x; 1.1682x over previous
//
#include <hip/hip_runtime.h>
#include <stdint.h>

#define SS 4096     // tokens per batch (H*W)
#define CC 64       // channels
#define BB 16       // batch

typedef unsigned short u16;
typedef __attribute__((ext_vector_type(8))) __bf16 bf16x8;
typedef __attribute__((ext_vector_type(8))) short short8;
typedef __attribute__((ext_vector_type(4))) float f32x4;

// pack two f32 -> two bf16 in one u32 (low = a, high = b), round-half-up
__device__ __forceinline__ uint32_t pkbf(float a, float b) {
    uint32_t ua = __float_as_uint(a) + 0x8000u;
    uint32_t ub = __float_as_uint(b) + 0x8000u;
    return __builtin_amdgcn_perm(ub, ua, 0x07060302u);
}

// load 8 consecutive fp32 weights -> bf16x8 fragment (L2-hot, once/block)
__device__ __forceinline__ bf16x8 ldw8(const float* p) {
    f32x4 lo = *(const f32x4*)(p);
    f32x4 hi = *(const f32x4*)(p + 4);
    union { uint32_t u[4]; bf16x8 v; } r;
    r.u[0] = pkbf(lo[0], lo[1]);
    r.u[1] = pkbf(lo[2], lo[3]);
    r.u[2] = pkbf(hi[0], hi[1]);
    r.u[3] = pkbf(hi[2], hi[3]);
    return r.v;
}

// ---------------------------------------------------------------------------
// Kernel A: QKV projection, barrier-free. x[B,C,S] fp32 -> Q (pre-scaled
// 0.125*log2e) / K [B,S,C] bf16, VT[B,C,S] bf16. Weights converted fp32->bf16
// in-kernel (16 KB/mat, L2-hot). Grid 1024 = 4 blocks/CU.
// ---------------------------------------------------------------------------
__global__ __launch_bounds__(256, 4) void qkv_kernel(
    const float* __restrict__ x,
    const float* __restrict__ qw, const float* __restrict__ qb,
    const float* __restrict__ kw, const float* __restrict__ kb,
    const float* __restrict__ vw, const float* __restrict__ vb,
    u16* __restrict__ Q, u16* __restrict__ K, u16* __restrict__ VT)
{
    const int b    = blockIdx.x & 15;
    const int s0   = (blockIdx.x >> 4) << 6;
    const int tid  = threadIdx.x;
    const int w    = tid >> 6;
    const int lane = tid & 63;
    const int lq   = lane & 15;
    const int quad = lane >> 4;

    __shared__ u16 bounce[4][16 * 72];     // per-wave, wave-private (no barrier)

    // per-lane x A-frag loads: lane needs x[c = kc*32+quad*8+j][s = sm]
    const int sm = s0 + w * 16 + lq;
    const float* xp = x + (size_t)b * CC * SS + sm;
    float xf[16];
#pragma unroll
    for (int kc = 0; kc < 2; ++kc)
#pragma unroll
        for (int j = 0; j < 8; ++j)
            xf[kc * 8 + j] = xp[(size_t)(kc * 32 + quad * 8 + j) * SS];

    union { uint32_t u[4]; bf16x8 v; } A0, A1;
#pragma unroll
    for (int p = 0; p < 4; ++p) {
        A0.u[p] = pkbf(xf[2 * p],     xf[2 * p + 1]);
        A1.u[p] = pkbf(xf[8 + 2 * p], xf[8 + 2 * p + 1]);
    }

    const float QSCALE = 0.125f * 1.44269504088896340736f;

    for (int m = 0; m < 3; ++m) {
        const float* bsrc = (m == 0) ? qb : ((m == 1) ? kb : vb);
        const float* wm   = (m == 0) ? qw : ((m == 1) ? kw : vw);
        bf16x8 bfr[2][4];
#pragma unroll
        for (int kc = 0; kc < 2; ++kc)
#pragma unroll
            for (int nt = 0; nt < 4; ++nt)
                bfr[kc][nt] = ldw8(wm + (nt * 16 + lq) * 64 + kc * 32 + quad * 8);

        f32x4 acc[4];
#pragma unroll
        for (int nt = 0; nt < 4; ++nt) {
            float bv = bsrc[nt * 16 + lq];
            acc[nt] = (f32x4){bv, bv, bv, bv};
        }
#pragma unroll
        for (int nt = 0; nt < 4; ++nt) {
            acc[nt] = __builtin_amdgcn_mfma_f32_16x16x32_bf16(A0.v, bfr[0][nt], acc[nt], 0, 0, 0);
            acc[nt] = __builtin_amdgcn_mfma_f32_16x16x32_bf16(A1.v, bfr[1][nt], acc[nt], 0, 0, 0);
        }

        if (m == 2) {
            // VT[b][c][s]: lane has col c, 4 consecutive s -> 8B store
#pragma unroll
            for (int nt = 0; nt < 4; ++nt) {
                int c = nt * 16 + lq;
                uint2 pv;
                pv.x = pkbf(acc[nt][0], acc[nt][1]);
                pv.y = pkbf(acc[nt][2], acc[nt][3]);
                *(uint2*)(VT + ((size_t)(b * CC + c)) * SS + s0 + w * 16 + quad * 4) = pv;
            }
        } else {
            const float scl = (m == 0) ? QSCALE : 1.0f;
            u16* bb = bounce[w];
#pragma unroll
            for (int nt = 0; nt < 4; ++nt)
#pragma unroll
                for (int r = 0; r < 4; ++r)
                    bb[(quad * 4 + r) * 72 + nt * 16 + lq] =
                        (u16)((__float_as_uint(acc[nt][r] * scl) + 0x8000u) >> 16);

            const int row = lane >> 2;
            const int ch  = (lane & 3) << 4;
            short8 v0 = *(const short8*)&bb[row * 72 + ch];       // wave-private RAW
            short8 v1 = *(const short8*)&bb[row * 72 + ch + 8];
            u16* dst = ((m == 0) ? Q : K) + ((size_t)(b * SS + s0 + w * 16 + row)) * CC + ch;
            *(short8*)dst = v0;
            *(short8*)(dst + 8) = v1;
        }
    }
}

// ---------------------------------------------------------------------------
// Kernel B: flash attention, SPLIT-KEY (fixed banking) + fused out-proj.
// 256 thr / 4 waves / 128 q per block. Wave w: query-half qh=w&1 (64 q as
// 4 groups of 16), key-half kh=w>>1 (32 keys of each 64-key tile).
// Per wave-iter LDS reads: 4 kf + 4 vf + 4 pf = 12 b128 (vs 20 in R5).
// P rows stride 36 u16 (72 B = 18 banks; 18*lq mod 32 covers all 16
// residues -> conflict-free writes, 2-way reads). K+V staged/double-
// buffered, one barrier/iter. Fixed-max softmax. Partials over key-halves
// merged once via LDS; kh=0 waves run the fused out-projection.
// ---------------------------------------------------------------------------
__global__ __launch_bounds__(256, 2) void flash_kernel(
    const u16* __restrict__ Q, const u16* __restrict__ K,
    const u16* __restrict__ Vt, const float* __restrict__ ow,
    const float* __restrict__ ob, float* __restrict__ out)
{
    const int b    = blockIdx.x & 15;          // batch-major: XCD gets 2 batches
    const int q0   = (blockIdx.x >> 4) << 7;   // 128 q per block
    const int tid  = threadIdx.x;
    const int w    = tid >> 6;
    const int qh   = w & 1;                    // query half (64 q)
    const int kh   = w >> 1;                   // key half (32 keys)
    const int lane = tid & 63;
    const int lq   = lane & 15;
    const int quad = lane >> 4;

    // carve one block: [0,8K) lds_k[2][4096] | [8K,16K) lds_v[2][4096]
    //                  | [16K,25216) lds_p[4][2304]
    // merge overlay: mb = 8704 f32 (34816 B) from 0; lpb at u16 17408.
    __shared__ u16 smem[25472];
    u16* lds_k = smem;                 // [buf*4096 + key*64 + c] swizzled
    u16* lds_v = smem + 8192;          // [buf*4096 + c*64 + key] swizzled
    u16* lds_pb = smem + 16384;        // [wave*2304 + q*36 + key_local]

    // Q B-frags: 4 groups, q = q0 + qh*64 + g*16 + lq
    bf16x8 qf[4][2];
#pragma unroll
    for (int g = 0; g < 4; ++g) {
        const u16* qp = Q + ((size_t)(b * SS + q0 + qh * 64 + g * 16 + lq)) * CC + quad * 8;
        qf[g][0] = *(const bf16x8*)(qp);
        qf[g][1] = *(const bf16x8*)(qp + 32);
    }

    f32x4 ot[4][4];                            // [group][ct] O^T partial (my key-half)
#pragma unroll
    for (int g = 0; g < 4; ++g)
#pragma unroll
        for (int ct = 0; ct < 4; ++ct) ot[g][ct] = (f32x4){0.f, 0.f, 0.f, 0.f};
    float lp[4] = {0.f, 0.f, 0.f, 0.f};

    // staging: thread covers row srow, 16B chunks 2a, 2a+1 (XOR-swizzled)
    const int srow = tid >> 2;
    const int a    = tid & 3;
    const u16* kg = K + ((size_t)(b * SS + srow)) * CC + a * 16;
    const u16* vg = Vt + ((size_t)(b * CC + srow)) * SS + a * 16;
    const int sw0 = srow * 64 + (((a << 1)    ) ^ (srow & 7)) * 8;
    const int sw1 = srow * 64 + (((a << 1) | 1) ^ (srow & 7)) * 8;

    {   // prologue: tile 0 -> buf 0
        short8 k0 = *(const short8*)(kg);
        short8 k1 = *(const short8*)(kg + 8);
        short8 v0 = *(const short8*)(vg);
        short8 v1 = *(const short8*)(vg + 8);
        *(short8*)&lds_k[sw0] = k0;
        *(short8*)&lds_k[sw1] = k1;
        *(short8*)&lds_v[sw0] = v0;
        *(short8*)&lds_v[sw1] = v1;
    }

    const int lsw = lq & 7;
    u16* pw = lds_pb + w * 2304;

    for (int kt = 0; kt < 64; ++kt) {
        __syncthreads();
        const int bo = (kt & 1) << 12;         // buffer offset in u16

        // prefetch tile kt+1 (consumed at end of body)
        const int ktn = (kt + 1) & 63;
        const u16* kgn = kg + (size_t)ktn * (64 * CC);
        const u16* vgn = vg + ktn * 64;
        short8 nk0 = *(const short8*)(kgn);
        short8 nk1 = *(const short8*)(kgn + 8);
        short8 nv0 = *(const short8*)(vgn);
        short8 nv1 = *(const short8*)(vgn + 8);

        // K frags (my 32-key half), loaded once, reused by 4 q-groups
        bf16x8 kf[2][2];
#pragma unroll
        for (int kc = 0; kc < 2; ++kc)
#pragma unroll
            for (int mt = 0; mt < 2; ++mt)
                kf[kc][mt] = *(const bf16x8*)
                    &lds_k[bo + (kh * 32 + mt * 16 + lq) * 64 + (((kc << 2) + quad) ^ lsw) * 8];

        // V^T frags (my 32-key half), loaded once, reused by 4 q-groups
        bf16x8 vf[4];
#pragma unroll
        for (int ct = 0; ct < 4; ++ct)
            vf[ct] = *(const bf16x8*)
                &lds_v[bo + (ct * 16 + lq) * 64 + (((kh << 2) + quad) ^ lsw) * 8];

        // S^T = K*Q^T -> softmax -> P rows (stride 36 u16, conflict-free)
#pragma unroll
        for (int g = 0; g < 4; ++g) {
            f32x4 sa[2];
            sa[0] = (f32x4){0.f, 0.f, 0.f, 0.f};
            sa[1] = (f32x4){0.f, 0.f, 0.f, 0.f};
#pragma unroll
            for (int kc = 0; kc < 2; ++kc)
#pragma unroll
                for (int mt = 0; mt < 2; ++mt)
                    sa[mt] = __builtin_amdgcn_mfma_f32_16x16x32_bf16(
                        kf[kc][mt], qf[g][kc], sa[mt], 0, 0, 0);

            const int pr = (g * 16 + lq) * 36;
#pragma unroll
            for (int mt = 0; mt < 2; ++mt) {
                float p0 = __builtin_amdgcn_exp2f(sa[mt][0]);
                float p1 = __builtin_amdgcn_exp2f(sa[mt][1]);
                float p2 = __builtin_amdgcn_exp2f(sa[mt][2]);
                float p3 = __builtin_amdgcn_exp2f(sa[mt][3]);
                lp[g] += (p0 + p1) + (p2 + p3);
                uint2 pv;
                pv.x = pkbf(p0, p1);
                pv.y = pkbf(p2, p3);
                *(uint2*)&pw[pr + mt * 16 + quad * 4] = pv;
            }
        }

        // PV: O^T += V^T * P^T (K-depth 32 = my key-half; one MFMA per g,ct)
#pragma unroll
        for (int g = 0; g < 4; ++g) {
            bf16x8 pf = *(const bf16x8*)&pw[(g * 16 + lq) * 36 + quad * 8];
#pragma unroll
            for (int ct = 0; ct < 4; ++ct)
                ot[g][ct] = __builtin_amdgcn_mfma_f32_16x16x32_bf16(
                    vf[ct], pf, ot[g][ct], 0, 0, 0);
        }

        // stage prefetched tile into the other buffer
        const int bn = 4096 - bo;
        *(short8*)&lds_k[bn + sw0] = nk0;
        *(short8*)&lds_k[bn + sw1] = nk1;
        *(short8*)&lds_v[bn + sw0] = nv0;
        *(short8*)&lds_v[bn + sw1] = nv1;
    }

    // ---- merge key-halves ----
#pragma unroll
    for (int g = 0; g < 4; ++g) {              // quad-reduce my 32-key partial l
        lp[g] += __shfl_xor(lp[g], 16);
        lp[g] += __shfl_xor(lp[g], 32);
    }

    float* mb  = (float*)smem;                 // [qh*64 + q][c], stride 68
    float* lpb = (float*)(smem + 17408);       // [qh*64 + q]

    __syncthreads();                           // kt-loop LDS dead
    if (kh == 1) {
#pragma unroll
        for (int g = 0; g < 4; ++g) {
#pragma unroll
            for (int ct = 0; ct < 4; ++ct)
                *(f32x4*)&mb[(qh * 64 + g * 16 + lq) * 68 + ct * 16 + quad * 4] = ot[g][ct];
            if (quad == 0) lpb[qh * 64 + g * 16 + lq] = lp[g];
        }
    }
    __syncthreads();

    if (kh == 0) {
        // out-projection weights (fp32 -> bf16 in-kernel) + bias
        bf16x8 wf[2][4];
#pragma unroll
        for (int kc = 0; kc < 2; ++kc)
#pragma unroll
            for (int nt = 0; nt < 4; ++nt)
                wf[kc][nt] = ldw8(ow + (nt * 16 + lq) * 64 + kc * 32 + quad * 8);
        float bias[4];
#pragma unroll
        for (int nt = 0; nt < 4; ++nt) bias[nt] = ob[nt * 16 + lq];

        // O bounce: reuse waves 2/3 P areas (dead, above mb overlay)
        u16* po = lds_pb + (2 + w) * 2304;     // 16 rows x 72 stride
#pragma unroll
        for (int g = 0; g < 4; ++g) {
            const float l = lp[g] + lpb[qh * 64 + g * 16 + lq];
            const float inv = 1.0f / l;

#pragma unroll
            for (int ct = 0; ct < 4; ++ct) {
                f32x4 o2 = *(const f32x4*)&mb[(qh * 64 + g * 16 + lq) * 68 + ct * 16 + quad * 4];
                uint2 pv;
                pv.x = pkbf((ot[g][ct][0] + o2[0]) * inv, (ot[g][ct][1] + o2[1]) * inv);
                pv.y = pkbf((ot[g][ct][2] + o2[2]) * inv, (ot[g][ct][3] + o2[3]) * inv);
                *(uint2*)&po[lq * 72 + ct * 16 + quad * 4] = pv;
            }
            bf16x8 oa0 = *(const bf16x8*)&po[lq * 72 + quad * 8];
            bf16x8 oa1 = *(const bf16x8*)&po[lq * 72 + 32 + quad * 8];

            f32x4 acc[4];
#pragma unroll
            for (int nt = 0; nt < 4; ++nt)
                acc[nt] = (f32x4){bias[nt], bias[nt], bias[nt], bias[nt]};
#pragma unroll
            for (int nt = 0; nt < 4; ++nt) {
                acc[nt] = __builtin_amdgcn_mfma_f32_16x16x32_bf16(oa0, wf[0][nt], acc[nt], 0, 0, 0);
                acc[nt] = __builtin_amdgcn_mfma_f32_16x16x32_bf16(oa1, wf[1][nt], acc[nt], 0, 0, 0);
            }
            // out[b][o][s]: lane has col o, 4 consecutive s -> f32x4 store
#pragma unroll
            for (int nt = 0; nt < 4; ++nt) {
                float* dst = out + ((size_t)(b * CC + nt * 16 + lq)) * SS
                           + q0 + qh * 64 + g * 16 + quad * 4;
                *(f32x4*)dst = acc[nt];
            }
        }
    }
}

// ---------------------------------------------------------------------------
extern "C" void kernel_launch(void* const* d_in, const int* in_sizes, int n_in,
                              void* d_out, int out_size, void* d_ws, size_t ws_size,
                              hipStream_t stream)
{
    const float* x  = (const float*)d_in[0];
    const float* qw = (const float*)d_in[1];
    const float* qb = (const float*)d_in[2];
    const float* kw = (const float*)d_in[3];
    const float* kb = (const float*)d_in[4];
    const float* vw = (const float*)d_in[5];
    const float* vb = (const float*)d_in[6];
    const float* ow = (const float*)d_in[7];
    const float* ob = (const float*)d_in[8];
    float* out = (float*)d_out;

    const size_t T = (size_t)BB * SS * CC;
    u16* Q  = (u16*)d_ws;
    u16* K  = Q + T;
    u16* VT = K + T;

    qkv_kernel<<<dim3(BB * 64), dim3(256), 0, stream>>>(x, qw, qb, kw, kb, vw, vb, Q, K, VT);
    flash_kernel<<<dim3(BB * 32), dim3(256), 0, stream>>>(Q, K, VT, ow, ob, out);
}

// Round 9
// 183.063 us; speedup vs baseline: 1.4322x; 1.2260x over previous
//
#include <hip/hip_runtime.h>
#include <stdint.h>

#define SS 4096     // tokens per batch (H*W)
#define CC 64       // channels
#define BB 16       // batch

typedef unsigned short u16;
typedef __attribute__((ext_vector_type(8))) __bf16 bf16x8;
typedef __attribute__((ext_vector_type(8))) short short8;
typedef __attribute__((ext_vector_type(4))) float f32x4;

// pack two f32 -> two bf16 in one u32 (low = a, high = b), round-half-up
__device__ __forceinline__ uint32_t pkbf(float a, float b) {
    uint32_t ua = __float_as_uint(a) + 0x8000u;
    uint32_t ub = __float_as_uint(b) + 0x8000u;
    return __builtin_amdgcn_perm(ub, ua, 0x07060302u);
}

// load 8 consecutive fp32 -> bf16x8 fragment (L2-hot, once/block)
__device__ __forceinline__ bf16x8 ldw8(const float* p) {
    f32x4 lo = *(const f32x4*)(p);
    f32x4 hi = *(const f32x4*)(p + 4);
    union { uint32_t u[4]; bf16x8 v; } r;
    r.u[0] = pkbf(lo[0], lo[1]);
    r.u[1] = pkbf(lo[2], lo[3]);
    r.u[2] = pkbf(hi[0], hi[1]);
    r.u[3] = pkbf(hi[2], hi[3]);
    return r.v;
}

// ---------------------------------------------------------------------------
// Kernel A: QKV projection, R2-style coalesced staging. x[B,C,S] fp32 ->
// Q[B,S,C] bf16 (pre-scaled 0.125*log2e), K[B,S,C] bf16, VT[B,C,S] bf16.
// 64 s/block, grid 1024 (4 blocks/CU). x staged via 256-B coalesced reads +
// LDS transpose; weights staged to LDS bf16 (coalesced reads). Q/K bounce
// reuses the dead x-tile after A-frags are in registers.
// ---------------------------------------------------------------------------
__global__ __launch_bounds__(256, 4) void qkv_kernel(
    const float* __restrict__ x,
    const float* __restrict__ qw, const float* __restrict__ qb,
    const float* __restrict__ kw, const float* __restrict__ kb,
    const float* __restrict__ vw, const float* __restrict__ vb,
    u16* __restrict__ Q, u16* __restrict__ K, u16* __restrict__ VT)
{
    const int b    = blockIdx.x & 15;          // batch-major for XCD locality
    const int s0   = (blockIdx.x >> 4) << 6;   // 64 s per block
    const int tid  = threadIdx.x;
    const int w    = tid >> 6;
    const int lane = tid & 63;
    const int lq   = lane & 15;
    const int quad = lane >> 4;

    __shared__ u16 wt[3][64 * 72];             // weights bf16 [o][c]
    __shared__ u16 xt[64 * 72];                // x-tile transposed [s][c]; later bounce

    // ---- stage weights bf16 (coalesced 512-B reads, conflict-spread writes) ----
    for (int m = 0; m < 3; ++m) {
        const float* wsrc = (m == 0) ? qw : ((m == 1) ? kw : vw);
#pragma unroll
        for (int i = 0; i < 8; ++i) {
            int p  = tid + (i << 8);           // pair index 0..2047
            int o  = p >> 5;
            int cp = p & 31;
            const float* wp = wsrc + o * 64 + cp * 2;
            ((uint32_t*)&wt[m][o * 72])[cp] = pkbf(wp[0], wp[1]);
        }
    }
    // ---- stage x-tile transposed (reads: 64 consecutive s = 256 B/instr) ----
    {
        const int sl = tid & 63;
        const int g  = tid >> 6;
        const float* xp = x + (size_t)b * CC * SS + s0 + sl;
#pragma unroll
        for (int i = 0; i < 8; ++i) {
            int p = g + (i << 2);              // c-pair 0..31
            float f0 = xp[(size_t)(2 * p) * SS];
            float f1 = xp[(size_t)(2 * p + 1) * SS];
            ((uint32_t*)&xt[sl * 72])[p] = pkbf(f0, f1);
        }
    }
    __syncthreads();

    // A-frags for my 16 s-rows
    bf16x8 a0 = *(const bf16x8*)&xt[(w * 16 + lq) * 72 + quad * 8];
    bf16x8 a1 = *(const bf16x8*)&xt[(w * 16 + lq) * 72 + 32 + quad * 8];
    __syncthreads();                           // xt dead -> reuse as bounce

    u16* bb = xt + w * (16 * 72);              // per-wave bounce

    const float QSCALE = 0.125f * 1.44269504088896340736f;

    for (int m = 0; m < 3; ++m) {
        const float* bsrc = (m == 0) ? qb : ((m == 1) ? kb : vb);
        bf16x8 bfr[2][4];
#pragma unroll
        for (int kc = 0; kc < 2; ++kc)
#pragma unroll
            for (int nt = 0; nt < 4; ++nt)
                bfr[kc][nt] = *(const bf16x8*)&wt[m][(nt * 16 + lq) * 72 + kc * 32 + quad * 8];

        f32x4 acc[4];
#pragma unroll
        for (int nt = 0; nt < 4; ++nt) {
            float bv = bsrc[nt * 16 + lq];
            acc[nt] = (f32x4){bv, bv, bv, bv};
        }
#pragma unroll
        for (int nt = 0; nt < 4; ++nt) {
            acc[nt] = __builtin_amdgcn_mfma_f32_16x16x32_bf16(a0, bfr[0][nt], acc[nt], 0, 0, 0);
            acc[nt] = __builtin_amdgcn_mfma_f32_16x16x32_bf16(a1, bfr[1][nt], acc[nt], 0, 0, 0);
        }

        if (m == 2) {
            // VT[b][c][s]: lane has col c, 4 consecutive s -> 8B store
#pragma unroll
            for (int nt = 0; nt < 4; ++nt) {
                int c = nt * 16 + lq;
                uint2 pv;
                pv.x = pkbf(acc[nt][0], acc[nt][1]);
                pv.y = pkbf(acc[nt][2], acc[nt][3]);
                *(uint2*)(VT + ((size_t)(b * CC + c)) * SS + s0 + w * 16 + quad * 4) = pv;
            }
        } else {
            const float scl = (m == 0) ? QSCALE : 1.0f;
#pragma unroll
            for (int nt = 0; nt < 4; ++nt)
#pragma unroll
                for (int r = 0; r < 4; ++r)
                    bb[(quad * 4 + r) * 72 + nt * 16 + lq] =
                        (u16)((__float_as_uint(acc[nt][r] * scl) + 0x8000u) >> 16);

            const int row = lane >> 2;
            const int ch  = (lane & 3) << 4;
            short8 v0 = *(const short8*)&bb[row * 72 + ch];       // wave-private RAW
            short8 v1 = *(const short8*)&bb[row * 72 + ch + 8];
            u16* dst = ((m == 0) ? Q : K) + ((size_t)(b * SS + s0 + w * 16 + row)) * CC + ch;
            *(short8*)dst = v0;
            *(short8*)(dst + 8) = v1;
        }
    }
}

// ---------------------------------------------------------------------------
// Kernel B: flash attention + fused out-projection. R5 structure (proven
// 106 us) + conflict-free P layout (64-u16 rows, 8-u16 chunk XOR by lq&7 —
// the R8-verified banking fix). 128 q/block, 2 q-groups/wave sharing K/V
// frags; K+V double-buffered, one barrier/iter; fixed-max softmax.
// ---------------------------------------------------------------------------
__global__ __launch_bounds__(256, 2) void flash_kernel(
    const u16* __restrict__ Q, const u16* __restrict__ K,
    const u16* __restrict__ Vt, const float* __restrict__ ow,
    const float* __restrict__ ob, float* __restrict__ out)
{
    const int b    = blockIdx.x & 15;          // batch-major: XCD gets 2 batches
    const int q0   = (blockIdx.x >> 4) << 7;   // 128 q per block
    const int tid  = threadIdx.x;
    const int w    = tid >> 6;
    const int lane = tid & 63;
    const int lq   = lane & 15;
    const int quad = lane >> 4;

    __shared__ u16 lds_k[2][64 * 64];          // K tile [key][c], chunk-XOR swizzled
    __shared__ u16 lds_v[2][64 * 64];          // V^T tile [c][key], swizzled
    __shared__ u16 lds_p[8][16 * 64];          // [wave][group] P / O bounce, swizzled

    // Q B-frags for both groups
    bf16x8 qf[2][2];
#pragma unroll
    for (int g = 0; g < 2; ++g) {
        const u16* qp = Q + ((size_t)(b * SS + q0 + g * 64 + w * 16 + lq)) * CC + quad * 8;
        qf[g][0] = *(const bf16x8*)(qp);
        qf[g][1] = *(const bf16x8*)(qp + 32);
    }

    f32x4 ot[2][4];
#pragma unroll
    for (int g = 0; g < 2; ++g)
#pragma unroll
        for (int ct = 0; ct < 4; ++ct) ot[g][ct] = (f32x4){0.f, 0.f, 0.f, 0.f};
    float lp[2][4] = {{0.f, 0.f, 0.f, 0.f}, {0.f, 0.f, 0.f, 0.f}};

    // staging: thread covers row srow, 16B chunks 2a, 2a+1 (XOR-swizzled)
    const int srow = tid >> 2;
    const int a    = tid & 3;
    const u16* kg = K + ((size_t)(b * SS + srow)) * CC + a * 16;
    const u16* vg = Vt + ((size_t)(b * CC + srow)) * SS + a * 16;
    const int sw0 = srow * 64 + (((a << 1)    ) ^ (srow & 7)) * 8;
    const int sw1 = srow * 64 + (((a << 1) | 1) ^ (srow & 7)) * 8;

    {   // prologue: tile 0 -> buf 0
        short8 k0 = *(const short8*)(kg);
        short8 k1 = *(const short8*)(kg + 8);
        short8 v0 = *(const short8*)(vg);
        short8 v1 = *(const short8*)(vg + 8);
        *(short8*)&lds_k[0][sw0] = k0;
        *(short8*)&lds_k[0][sw1] = k1;
        *(short8*)&lds_v[0][sw0] = v0;
        *(short8*)&lds_v[0][sw1] = v1;
    }

    const int lsw = lq & 7;
    u16* pw0 = lds_p[(w << 1)];
    u16* pw1 = lds_p[(w << 1) | 1];

    for (int kt = 0; kt < 64; ++kt) {
        __syncthreads();
        const int buf = kt & 1;

        // prefetch tile kt+1 (consumed at end of body)
        const int ktn = (kt + 1) & 63;
        const u16* kgn = kg + (size_t)ktn * (64 * CC);
        const u16* vgn = vg + ktn * 64;
        short8 nk0 = *(const short8*)(kgn);
        short8 nk1 = *(const short8*)(kgn + 8);
        short8 nv0 = *(const short8*)(vgn);
        short8 nv1 = *(const short8*)(vgn + 8);

        // K frags loaded ONCE, feed both q-groups
        bf16x8 kf[2][4];
#pragma unroll
        for (int kc = 0; kc < 2; ++kc)
#pragma unroll
            for (int mt = 0; mt < 4; ++mt)
                kf[kc][mt] = *(const bf16x8*)
                    &lds_k[buf][(mt * 16 + lq) * 64 + (((kc << 2) + quad) ^ lsw) * 8];

        // S^T = K * Q^T for both groups
        f32x4 sa[2][4];
#pragma unroll
        for (int g = 0; g < 2; ++g)
#pragma unroll
            for (int mt = 0; mt < 4; ++mt) sa[g][mt] = (f32x4){0.f, 0.f, 0.f, 0.f};
#pragma unroll
        for (int g = 0; g < 2; ++g)
#pragma unroll
            for (int kc = 0; kc < 2; ++kc)
#pragma unroll
                for (int mt = 0; mt < 4; ++mt)
                    sa[g][mt] = __builtin_amdgcn_mfma_f32_16x16x32_bf16(
                        kf[kc][mt], qf[g][kc], sa[g][mt], 0, 0, 0);

        // softmax (fixed max): p = exp2(s); P rows -> swizzled LDS
#pragma unroll
        for (int g = 0; g < 2; ++g) {
            u16* pw = g ? pw1 : pw0;
#pragma unroll
            for (int mt = 0; mt < 4; ++mt) {
                float p0 = __builtin_amdgcn_exp2f(sa[g][mt][0]);
                float p1 = __builtin_amdgcn_exp2f(sa[g][mt][1]);
                float p2 = __builtin_amdgcn_exp2f(sa[g][mt][2]);
                float p3 = __builtin_amdgcn_exp2f(sa[g][mt][3]);
                lp[g][0] += p0; lp[g][1] += p1; lp[g][2] += p2; lp[g][3] += p3;
                uint2 pv;
                pv.x = pkbf(p0, p1);
                pv.y = pkbf(p2, p3);
                *(uint2*)&pw[lq * 64 + (((mt * 2 + (quad >> 1)) ^ lsw) << 3) + (quad & 1) * 4] = pv;
            }
        }

        // V frags loaded ONCE, feed both groups
        bf16x8 vf[2][4];
#pragma unroll
        for (int kc = 0; kc < 2; ++kc)
#pragma unroll
            for (int ct = 0; ct < 4; ++ct)
                vf[kc][ct] = *(const bf16x8*)
                    &lds_v[buf][(ct * 16 + lq) * 64 + (((kc << 2) + quad) ^ lsw) * 8];

        // O^T += V^T * P^T per group
#pragma unroll
        for (int g = 0; g < 2; ++g) {
            const u16* pw = g ? pw1 : pw0;
#pragma unroll
            for (int kc = 0; kc < 2; ++kc) {
                bf16x8 pf = *(const bf16x8*)
                    &pw[lq * 64 + (((kc * 4 + quad) ^ lsw) << 3)];
#pragma unroll
                for (int ct = 0; ct < 4; ++ct)
                    ot[g][ct] = __builtin_amdgcn_mfma_f32_16x16x32_bf16(
                        vf[kc][ct], pf, ot[g][ct], 0, 0, 0);
            }
        }

        // stage prefetched tile into other buffer
        u16* lkd = lds_k[buf ^ 1];
        u16* lvd = lds_v[buf ^ 1];
        *(short8*)&lkd[sw0] = nk0;
        *(short8*)&lkd[sw1] = nk1;
        *(short8*)&lvd[sw0] = nv0;
        *(short8*)&lvd[sw1] = nv1;
    }

    // ---- fused out-projection epilogue ----
    bf16x8 wf[2][4];
#pragma unroll
    for (int kc = 0; kc < 2; ++kc)
#pragma unroll
        for (int nt = 0; nt < 4; ++nt)
            wf[kc][nt] = ldw8(ow + (nt * 16 + lq) * 64 + kc * 32 + quad * 8);
    float bias[4];
#pragma unroll
    for (int nt = 0; nt < 4; ++nt) bias[nt] = ob[nt * 16 + lq];

#pragma unroll
    for (int g = 0; g < 2; ++g) {
        float l = (lp[g][0] + lp[g][1]) + (lp[g][2] + lp[g][3]);
        l += __shfl_xor(l, 16);
        l += __shfl_xor(l, 32);
        const float inv = 1.0f / l;

        u16* po = g ? pw1 : pw0;
#pragma unroll
        for (int ct = 0; ct < 4; ++ct) {
            uint2 pv;
            pv.x = pkbf(ot[g][ct][0] * inv, ot[g][ct][1] * inv);
            pv.y = pkbf(ot[g][ct][2] * inv, ot[g][ct][3] * inv);
            *(uint2*)&po[lq * 64 + (((ct * 2 + (quad >> 1)) ^ lsw) << 3) + (quad & 1) * 4] = pv;
        }
        bf16x8 oa0 = *(const bf16x8*)&po[lq * 64 + (((0 * 4 + quad) ^ lsw) << 3)];
        bf16x8 oa1 = *(const bf16x8*)&po[lq * 64 + (((1 * 4 + quad) ^ lsw) << 3)];

        f32x4 acc[4];
#pragma unroll
        for (int nt = 0; nt < 4; ++nt)
            acc[nt] = (f32x4){bias[nt], bias[nt], bias[nt], bias[nt]};
#pragma unroll
        for (int nt = 0; nt < 4; ++nt) {
            acc[nt] = __builtin_amdgcn_mfma_f32_16x16x32_bf16(oa0, wf[0][nt], acc[nt], 0, 0, 0);
            acc[nt] = __builtin_amdgcn_mfma_f32_16x16x32_bf16(oa1, wf[1][nt], acc[nt], 0, 0, 0);
        }
#pragma unroll
        for (int nt = 0; nt < 4; ++nt) {
            float* dst = out + ((size_t)(b * CC + nt * 16 + lq)) * SS
                       + q0 + g * 64 + w * 16 + quad * 4;
            *(f32x4*)dst = acc[nt];
        }
    }
}

// ---------------------------------------------------------------------------
extern "C" void kernel_launch(void* const* d_in, const int* in_sizes, int n_in,
                              void* d_out, int out_size, void* d_ws, size_t ws_size,
                              hipStream_t stream)
{
    const float* x  = (const float*)d_in[0];
    const float* qw = (const float*)d_in[1];
    const float* qb = (const float*)d_in[2];
    const float* kw = (const float*)d_in[3];
    const float* kb = (const float*)d_in[4];
    const float* vw = (const float*)d_in[5];
    const float* vb = (const float*)d_in[6];
    const float* ow = (const float*)d_in[7];
    const float* ob = (const float*)d_in[8];
    float* out = (float*)d_out;

    const size_t T = (size_t)BB * SS * CC;
    u16* Q  = (u16*)d_ws;
    u16* K  = Q + T;
    u16* VT = K + T;

    qkv_kernel<<<dim3(BB * 64), dim3(256), 0, stream>>>(x, qw, qb, kw, kb, vw, vb, Q, K, VT);
    flash_kernel<<<dim3(BB * 32), dim3(256), 0, stream>>>(Q, K, VT, ow, ob, out);
}